// Round 1
// baseline (1173.979 us; speedup 1.0000x reference)
//
#include <hip/hip_runtime.h>
#include <math.h>

// SingleGAP: per-point tiny MLPs + GLOBAL softmax over N (axis 0, faithful bug),
// then attention-weighted sum. out0 = [N][16] x_attn, out1 = [N][160] h2 (flat).

__device__ __forceinline__ void comb(float& m, float& s, float om, float os) {
  float M = fmaxf(m, om);
  if (M == -INFINITY) return;  // both empty
  s = s * __expf(m - M) + os * __expf(om - M);
  m = M;
}

__global__ __launch_bounds__(256) void gap_k1(
    const float* __restrict__ xknn, const float* __restrict__ x,
    const float* __restrict__ Wf, const float* __restrict__ bf,
    const float* __restrict__ W1, const float* __restrict__ b1p,
    float* __restrict__ out, float* __restrict__ partials, int n) {
  // LDS: x2 tile per point padded: d-row stride 12 (16B aligned), point stride 196
  // (196%32=4 -> the 4 p-groups of a wave land on distinct banks; 16-lane broadcast free)
  __shared__ float s_x2[16][196];
  __shared__ float s_x[16][16];
  __shared__ float s_wf[256];
  __shared__ float s_misc[33];        // [0..15]=bf, [16..31]=W1, [32]=b1
  __shared__ float s_red[4][10][2];

  const int tid = threadIdx.x;
  const int p = tid >> 4;   // local point 0..15
  const int f = tid & 15;   // feature 0..15

  s_wf[tid] = Wf[tid];
  if (tid < 16) s_misc[tid] = bf[tid];
  else if (tid < 32) s_misc[tid] = W1[tid - 16];
  else if (tid == 32) s_misc[32] = b1p[0];
  __syncthreads();

  float wfrow[16];
#pragma unroll
  for (int d = 0; d < 16; ++d) wfrow[d] = s_wf[f * 16 + d];
  const float bff = s_misc[f];
  const float w1f = s_misc[16 + f];
  const float b1v = s_misc[32];

  float run_m = -INFINITY, run_s = 0.f;  // online softmax state for k == f (f<10)

  float* out0 = out;                       // [n][16]  (logits now, x_attn after K3)
  float* out1 = out + (size_t)n * 16;      // [n][160] h2 flat

  for (int base = blockIdx.x * 16; base < n; base += gridDim.x * 16) {
    __syncthreads();  // protect LDS from previous iteration's readers
    const int npts = min(16, n - base);
    const int nf4 = npts * 40;
    for (int idx4 = tid; idx4 < nf4; idx4 += 256) {
      float4 v = *(const float4*)(xknn + (size_t)base * 160 + (size_t)idx4 * 4);
      int pl = idx4 / 40;
      int r0 = (idx4 - pl * 40) * 4;
      float vv[4] = {v.x, v.y, v.z, v.w};
#pragma unroll
      for (int j = 0; j < 4; ++j) {
        int r = r0 + j;
        int d = r / 10;
        int kk = r - d * 10;
        s_x2[pl][d * 12 + kk] = vv[j];
      }
    }
    if (tid < npts * 4) {
      int pl = tid >> 2, c = tid & 3;
      *(float4*)(&s_x[pl][c * 4]) =
          *(const float4*)(x + (size_t)(base + pl) * 16 + (size_t)c * 4);
    }
    __syncthreads();

    // h2[f][k] for own f
    float h2f[10];
#pragma unroll
    for (int k = 0; k < 10; ++k) h2f[k] = bff;
#pragma unroll
    for (int d = 0; d < 16; ++d) {
      const float* r = &s_x2[p][d * 12];
      float w = wfrow[d];
      float4 xa = *(const float4*)(r);
      float4 xb = *(const float4*)(r + 4);
      float2 xc2 = *(const float2*)(r + 8);
      h2f[0] = fmaf(w, xa.x, h2f[0]);
      h2f[1] = fmaf(w, xa.y, h2f[1]);
      h2f[2] = fmaf(w, xa.z, h2f[2]);
      h2f[3] = fmaf(w, xa.w, h2f[3]);
      h2f[4] = fmaf(w, xb.x, h2f[4]);
      h2f[5] = fmaf(w, xb.y, h2f[5]);
      h2f[6] = fmaf(w, xb.z, h2f[6]);
      h2f[7] = fmaf(w, xb.w, h2f[7]);
      h2f[8] = fmaf(w, xc2.x, h2f[8]);
      h2f[9] = fmaf(w, xc2.y, h2f[9]);
    }

    // a2[k] = sum_f W1[f]*h2[f][k]  (butterfly over the 16-lane f-group)
    float a2[10];
#pragma unroll
    for (int k = 0; k < 10; ++k) a2[k] = w1f * h2f[k];
#pragma unroll
    for (int mask = 1; mask < 16; mask <<= 1) {
#pragma unroll
      for (int k = 0; k < 10; ++k) a2[k] += __shfl_xor(a2[k], mask, 16);
    }

    // a1 from center point
    float h1f = bff;
#pragma unroll
    for (int d = 0; d < 16; ++d) h1f = fmaf(wfrow[d], s_x[p][d], h1f);
    float a1p = w1f * h1f;
#pragma unroll
    for (int mask = 1; mask < 16; mask <<= 1) a1p += __shfl_xor(a1p, mask, 16);

    const float addc = a1p + 2.0f * b1v;  // logit = (a2sum + b1) + (a1sum + b1)

    const int pt = base + p;
    if (pt < n) {
      // write h2 (== output1 flat, and == x2v flat)
      float* o1 = out1 + (size_t)pt * 160 + f * 10;
      *(float2*)(o1 + 0) = make_float2(h2f[0], h2f[1]);
      *(float2*)(o1 + 2) = make_float2(h2f[2], h2f[3]);
      *(float2*)(o1 + 4) = make_float2(h2f[4], h2f[5]);
      *(float2*)(o1 + 6) = make_float2(h2f[6], h2f[7]);
      *(float2*)(o1 + 8) = make_float2(h2f[8], h2f[9]);
      if (f < 10) {
        // lane f takes logit k=f (compile-time select chain, no scratch)
        float lsel = a2[0];
#pragma unroll
        for (int k = 1; k < 10; ++k) lsel = (f == k) ? a2[k] : lsel;
        lsel += addc;
        out0[(size_t)pt * 16 + f] = lsel;  // stash logit in out0; K3 overwrites
        comb(run_m, run_s, lsel, 1.0f);
      }
    }
  }

  // combine (m,s) across the 4 p-groups in each wave (lanes differ in bits 4,5)
#pragma unroll
  for (int mask = 16; mask < 64; mask <<= 1) {
    float om = __shfl_xor(run_m, mask, 64);
    float os = __shfl_xor(run_s, mask, 64);
    comb(run_m, run_s, om, os);
  }
  const int wave = tid >> 6, lane = tid & 63;
  __syncthreads();
  if (lane < 10) { s_red[wave][lane][0] = run_m; s_red[wave][lane][1] = run_s; }
  __syncthreads();
  if (tid < 10) {
    float m = s_red[0][tid][0], s = s_red[0][tid][1];
    comb(m, s, s_red[1][tid][0], s_red[1][tid][1]);
    comb(m, s, s_red[2][tid][0], s_red[2][tid][1]);
    comb(m, s, s_red[3][tid][0], s_red[3][tid][1]);
    partials[(size_t)blockIdx.x * 20 + tid * 2 + 0] = m;
    partials[(size_t)blockIdx.x * 20 + tid * 2 + 1] = s;
  }
}

__global__ __launch_bounds__(256) void gap_k2(const float* __restrict__ part,
                                              int nb, float* __restrict__ fin) {
  const int k = blockIdx.x;   // one block per k-slot
  const int tid = threadIdx.x;
  float m = -INFINITY, s = 0.f;
  for (int i = tid; i < nb; i += 256)
    comb(m, s, part[(size_t)i * 20 + k * 2], part[(size_t)i * 20 + k * 2 + 1]);
#pragma unroll
  for (int mask = 1; mask < 64; mask <<= 1) {
    float om = __shfl_xor(m, mask, 64);
    float os = __shfl_xor(s, mask, 64);
    comb(m, s, om, os);
  }
  __shared__ float sm[4][2];
  const int wave = tid >> 6, lane = tid & 63;
  if (lane == 0) { sm[wave][0] = m; sm[wave][1] = s; }
  __syncthreads();
  if (tid == 0) {
    for (int w = 1; w < 4; ++w) comb(m, s, sm[w][0], sm[w][1]);
    fin[k * 2 + 0] = m;
    fin[k * 2 + 1] = s;
  }
}

__global__ __launch_bounds__(256) void gap_k3(const float* __restrict__ fin,
                                              float* __restrict__ out, int n) {
  float mk[10], rsk[10];
#pragma unroll
  for (int k = 0; k < 10; ++k) {
    mk[k] = fin[2 * k];
    rsk[k] = 1.0f / fin[2 * k + 1];
  }
  float* out0 = out;
  const float* out1 = out + (size_t)n * 16;
  for (long i = (long)blockIdx.x * 256 + threadIdx.x; i < n;
       i += (long)gridDim.x * 256) {
    float* lrow = out0 + i * 16;
    float4 la = *(const float4*)(lrow);
    float4 lb = *(const float4*)(lrow + 4);
    float2 lc = *(const float2*)(lrow + 8);
    float l[10] = {la.x, la.y, la.z, la.w, lb.x, lb.y, lb.z, lb.w, lc.x, lc.y};
    float w[10];
#pragma unroll
    for (int k = 0; k < 10; ++k) w[k] = __expf(l[k] - mk[k]) * rsk[k];
    const float* vrow = out1 + i * 160;
    float4 a0 = make_float4(0, 0, 0, 0), a1 = a0, a2 = a0, a3 = a0;
#pragma unroll
    for (int k = 0; k < 10; ++k) {
      float wk = w[k];
      float4 v0 = *(const float4*)(vrow + k * 16 + 0);
      float4 v1 = *(const float4*)(vrow + k * 16 + 4);
      float4 v2 = *(const float4*)(vrow + k * 16 + 8);
      float4 v3 = *(const float4*)(vrow + k * 16 + 12);
      a0.x = fmaf(wk, v0.x, a0.x); a0.y = fmaf(wk, v0.y, a0.y);
      a0.z = fmaf(wk, v0.z, a0.z); a0.w = fmaf(wk, v0.w, a0.w);
      a1.x = fmaf(wk, v1.x, a1.x); a1.y = fmaf(wk, v1.y, a1.y);
      a1.z = fmaf(wk, v1.z, a1.z); a1.w = fmaf(wk, v1.w, a1.w);
      a2.x = fmaf(wk, v2.x, a2.x); a2.y = fmaf(wk, v2.y, a2.y);
      a2.z = fmaf(wk, v2.z, a2.z); a2.w = fmaf(wk, v2.w, a2.w);
      a3.x = fmaf(wk, v3.x, a3.x); a3.y = fmaf(wk, v3.y, a3.y);
      a3.z = fmaf(wk, v3.z, a3.z); a3.w = fmaf(wk, v3.w, a3.w);
    }
    *(float4*)(lrow + 0) = a0;
    *(float4*)(lrow + 4) = a1;
    *(float4*)(lrow + 8) = a2;
    *(float4*)(lrow + 12) = a3;
  }
}

extern "C" void kernel_launch(void* const* d_in, const int* in_sizes, int n_in,
                              void* d_out, int out_size, void* d_ws, size_t ws_size,
                              hipStream_t stream) {
  const float* xknn = (const float*)d_in[0];
  const float* x    = (const float*)d_in[1];
  const float* Wf   = (const float*)d_in[2];
  const float* bf   = (const float*)d_in[3];
  const float* W1   = (const float*)d_in[4];
  const float* b1   = (const float*)d_in[5];
  float* out = (float*)d_out;
  const int n = in_sizes[1] / 16;  // x is [N][16]

  const int G1 = 2048;
  float* partials = (float*)d_ws;                 // [G1][10][2]
  float* finals = partials + (size_t)G1 * 20;     // [10][2]

  gap_k1<<<G1, 256, 0, stream>>>(xknn, x, Wf, bf, W1, b1, out, partials, n);
  gap_k2<<<10, 256, 0, stream>>>(partials, G1, finals);
  gap_k3<<<2048, 256, 0, stream>>>(finals, out, n);
}

// Round 2
// 584.548 us; speedup vs baseline: 2.0084x; 2.0084x over previous
//
#include <hip/hip_runtime.h>
#include <math.h>

// SingleGAP: per-point tiny MLPs + GLOBAL softmax over N (axis 0, faithful bug),
// then attention-weighted sum. out0 = [N][16] x_attn, out1 = [N][160] h2 (flat).

__device__ __forceinline__ void comb(float& m, float& s, float om, float os) {
  float M = fmaxf(m, om);
  if (M == -INFINITY) return;  // both empty
  s = s * __expf(m - M) + os * __expf(om - M);
  m = M;
}

__global__ __launch_bounds__(256) void gap_k1(
    const float* __restrict__ xknn, const float* __restrict__ x,
    const float* __restrict__ Wf, const float* __restrict__ bf,
    const float* __restrict__ W1, const float* __restrict__ b1p,
    float* __restrict__ out, float* __restrict__ partials, int n) {
  // LDS: x2 tile per point padded: d-row stride 12 (16B aligned), point stride 196
  __shared__ float s_x2[16][196];
  __shared__ float s_x[16][16];
  __shared__ float s_wf[256];
  __shared__ float s_misc[33];        // [0..15]=bf, [16..31]=W1, [32]=b1
  __shared__ float s_red[4][10][2];

  const int tid = threadIdx.x;
  const int p = tid >> 4;   // local point 0..15
  const int f = tid & 15;   // feature 0..15

  s_wf[tid] = Wf[tid];
  if (tid < 16) s_misc[tid] = bf[tid];
  else if (tid < 32) s_misc[tid] = W1[tid - 16];
  else if (tid == 32) s_misc[32] = b1p[0];
  __syncthreads();

  float wfrow[16];
#pragma unroll
  for (int d = 0; d < 16; ++d) wfrow[d] = s_wf[f * 16 + d];
  const float bff = s_misc[f];
  const float w1f = s_misc[16 + f];
  const float b1v = s_misc[32];

  float run_m = -INFINITY, run_s = 0.f;  // online softmax state for k == f (f<10)

  float* out0 = out;                       // [n][16]  (logits now, x_attn after K3)
  float* out1 = out + (size_t)n * 16;      // [n][160] h2 flat

  for (int base = blockIdx.x * 16; base < n; base += gridDim.x * 16) {
    __syncthreads();  // protect LDS from previous iteration's readers
    const int npts = min(16, n - base);
    const int nf4 = npts * 40;
    for (int idx4 = tid; idx4 < nf4; idx4 += 256) {
      float4 v = *(const float4*)(xknn + (size_t)base * 160 + (size_t)idx4 * 4);
      int pl = idx4 / 40;
      int r0 = (idx4 - pl * 40) * 4;
      float vv[4] = {v.x, v.y, v.z, v.w};
#pragma unroll
      for (int j = 0; j < 4; ++j) {
        int r = r0 + j;
        int d = r / 10;
        int kk = r - d * 10;
        s_x2[pl][d * 12 + kk] = vv[j];
      }
    }
    if (tid < npts * 4) {
      int pl = tid >> 2, c = tid & 3;
      *(float4*)(&s_x[pl][c * 4]) =
          *(const float4*)(x + (size_t)(base + pl) * 16 + (size_t)c * 4);
    }
    __syncthreads();

    // h2[f][k] for own f
    float h2f[10];
#pragma unroll
    for (int k = 0; k < 10; ++k) h2f[k] = bff;
#pragma unroll
    for (int d = 0; d < 16; ++d) {
      const float* r = &s_x2[p][d * 12];
      float w = wfrow[d];
      float4 xa = *(const float4*)(r);
      float4 xb = *(const float4*)(r + 4);
      float2 xc2 = *(const float2*)(r + 8);
      h2f[0] = fmaf(w, xa.x, h2f[0]);
      h2f[1] = fmaf(w, xa.y, h2f[1]);
      h2f[2] = fmaf(w, xa.z, h2f[2]);
      h2f[3] = fmaf(w, xa.w, h2f[3]);
      h2f[4] = fmaf(w, xb.x, h2f[4]);
      h2f[5] = fmaf(w, xb.y, h2f[5]);
      h2f[6] = fmaf(w, xb.z, h2f[6]);
      h2f[7] = fmaf(w, xb.w, h2f[7]);
      h2f[8] = fmaf(w, xc2.x, h2f[8]);
      h2f[9] = fmaf(w, xc2.y, h2f[9]);
    }

    // a2[k] = sum_f W1[f]*h2[f][k]  (butterfly over the 16-lane f-group)
    float a2[10];
#pragma unroll
    for (int k = 0; k < 10; ++k) a2[k] = w1f * h2f[k];
#pragma unroll
    for (int mask = 1; mask < 16; mask <<= 1) {
#pragma unroll
      for (int k = 0; k < 10; ++k) a2[k] += __shfl_xor(a2[k], mask, 16);
    }

    // a1 from center point
    float h1f = bff;
#pragma unroll
    for (int d = 0; d < 16; ++d) h1f = fmaf(wfrow[d], s_x[p][d], h1f);
    float a1p = w1f * h1f;
#pragma unroll
    for (int mask = 1; mask < 16; mask <<= 1) a1p += __shfl_xor(a1p, mask, 16);

    const float addc = a1p + 2.0f * b1v;  // logit = (a2sum + b1) + (a1sum + b1)

    const int pt = base + p;
    if (pt < n) {
      // write h2 (== output1 flat, and == x2v flat)
      float* o1 = out1 + (size_t)pt * 160 + f * 10;
      *(float2*)(o1 + 0) = make_float2(h2f[0], h2f[1]);
      *(float2*)(o1 + 2) = make_float2(h2f[2], h2f[3]);
      *(float2*)(o1 + 4) = make_float2(h2f[4], h2f[5]);
      *(float2*)(o1 + 6) = make_float2(h2f[6], h2f[7]);
      *(float2*)(o1 + 8) = make_float2(h2f[8], h2f[9]);
      if (f < 10) {
        // lane f takes logit k=f (compile-time select chain, no scratch)
        float lsel = a2[0];
#pragma unroll
        for (int k = 1; k < 10; ++k) lsel = (f == k) ? a2[k] : lsel;
        lsel += addc;
        out0[(size_t)pt * 16 + f] = lsel;  // stash logit in out0; K3 overwrites
        comb(run_m, run_s, lsel, 1.0f);
      }
    }
  }

  // combine (m,s) across the 4 p-groups in each wave (lanes differ in bits 4,5)
#pragma unroll
  for (int mask = 16; mask < 64; mask <<= 1) {
    float om = __shfl_xor(run_m, mask, 64);
    float os = __shfl_xor(run_s, mask, 64);
    comb(run_m, run_s, om, os);
  }
  const int wave = tid >> 6, lane = tid & 63;
  __syncthreads();
  if (lane < 10) { s_red[wave][lane][0] = run_m; s_red[wave][lane][1] = run_s; }
  __syncthreads();
  if (tid < 10) {
    float m = s_red[0][tid][0], s = s_red[0][tid][1];
    comb(m, s, s_red[1][tid][0], s_red[1][tid][1]);
    comb(m, s, s_red[2][tid][0], s_red[2][tid][1]);
    comb(m, s, s_red[3][tid][0], s_red[3][tid][1]);
    partials[(size_t)blockIdx.x * 20 + tid * 2 + 0] = m;
    partials[(size_t)blockIdx.x * 20 + tid * 2 + 1] = s;
  }
}

__global__ __launch_bounds__(256) void gap_k2(const float* __restrict__ part,
                                              int nb, float* __restrict__ fin) {
  const int k = blockIdx.x;   // one block per k-slot
  const int tid = threadIdx.x;
  float m = -INFINITY, s = 0.f;
  for (int i = tid; i < nb; i += 256)
    comb(m, s, part[(size_t)i * 20 + k * 2], part[(size_t)i * 20 + k * 2 + 1]);
#pragma unroll
  for (int mask = 1; mask < 64; mask <<= 1) {
    float om = __shfl_xor(m, mask, 64);
    float os = __shfl_xor(s, mask, 64);
    comb(m, s, om, os);
  }
  __shared__ float sm[4][2];
  const int wave = tid >> 6, lane = tid & 63;
  if (lane == 0) { sm[wave][0] = m; sm[wave][1] = s; }
  __syncthreads();
  if (tid == 0) {
    for (int w = 1; w < 4; ++w) comb(m, s, sm[w][0], sm[w][1]);
    fin[k * 2 + 0] = m;
    fin[k * 2 + 1] = s;
  }
}

// K3: 4 lanes per point. Lane (p,q) accumulates features f = q*4..q*4+3.
// For fixed k, the quad's loads cover exactly one 64B sector of h2flat;
// the wave's 16 points cover 16 full sectors per instruction -> no over-fetch.
__global__ __launch_bounds__(256) void gap_k3(const float* __restrict__ fin,
                                              float* __restrict__ out, int n) {
  __shared__ float s_fin[20];
  if (threadIdx.x < 20) s_fin[threadIdx.x] = fin[threadIdx.x];
  __syncthreads();
  float mk[10], rsk[10];
#pragma unroll
  for (int k = 0; k < 10; ++k) {
    mk[k] = s_fin[2 * k];
    rsk[k] = 1.0f / s_fin[2 * k + 1];
  }
  float* out0 = out;
  const float* out1 = out + (size_t)n * 16;
  const int q = threadIdx.x & 3;
  const int pl = threadIdx.x >> 2;           // 64 points per block pass
  for (long i = (long)blockIdx.x * 64 + pl; i < n; i += (long)gridDim.x * 64) {
    float* lrow = out0 + i * 16;
    // all 4 lanes of the quad read the same 64B logit line (L1 broadcast)
    float4 la = *(const float4*)(lrow);
    float4 lb = *(const float4*)(lrow + 4);
    float2 lc = *(const float2*)(lrow + 8);
    float l[10] = {la.x, la.y, la.z, la.w, lb.x, lb.y, lb.z, lb.w, lc.x, lc.y};
    float w[10];
#pragma unroll
    for (int k = 0; k < 10; ++k) w[k] = __expf(l[k] - mk[k]) * rsk[k];
    const float* vrow = out1 + i * 160 + q * 4;
    float4 acc = make_float4(0.f, 0.f, 0.f, 0.f);
#pragma unroll
    for (int k = 0; k < 10; ++k) {
      float4 v = *(const float4*)(vrow + k * 16);
      float wk = w[k];
      acc.x = fmaf(wk, v.x, acc.x);
      acc.y = fmaf(wk, v.y, acc.y);
      acc.z = fmaf(wk, v.z, acc.z);
      acc.w = fmaf(wk, v.w, acc.w);
    }
    // store after all reads (wave-lockstep => no RAW hazard on the logit line)
    *(float4*)(lrow + q * 4) = acc;
  }
}

extern "C" void kernel_launch(void* const* d_in, const int* in_sizes, int n_in,
                              void* d_out, int out_size, void* d_ws, size_t ws_size,
                              hipStream_t stream) {
  const float* xknn = (const float*)d_in[0];
  const float* x    = (const float*)d_in[1];
  const float* Wf   = (const float*)d_in[2];
  const float* bf   = (const float*)d_in[3];
  const float* W1   = (const float*)d_in[4];
  const float* b1   = (const float*)d_in[5];
  float* out = (float*)d_out;
  const int n = in_sizes[1] / 16;  // x is [N][16]

  const int G1 = 2048;
  float* partials = (float*)d_ws;                 // [G1][10][2]
  float* finals = partials + (size_t)G1 * 20;     // [10][2]

  gap_k1<<<G1, 256, 0, stream>>>(xknn, x, Wf, bf, W1, b1, out, partials, n);
  gap_k2<<<10, 256, 0, stream>>>(partials, G1, finals);
  gap_k3<<<2048, 256, 0, stream>>>(finals, out, n);
}